// Round 8
// baseline (2129.207 us; speedup 1.0000x reference)
//
#include <hip/hip_runtime.h>
#include <math.h>

#define NB     262144   // batch (tokens)
#define DD     512      // d_routing
#define NG     4        // groups
#define NGS    4        // group size
#define NOUT   20       // 4 group logits + 16 in-group logits

#define TPB    256      // threads per block (4 waves) -- 8 waves/CU at 2 blocks
#define TOKS   256      // tokens per block (1 per thread)
#define CH     32       // floats of D per chunk per token (one full 128B line)
#define NCHUNK 16       // DD / CH
#define GRP    260      // 8 tokens * 32 floats + 4 pad floats (bank spread)
#define NXG    32       // staging groups per chunk (TOKS/8)
#define WROWS  24       // 20 weight rows padded to 24 (3 full instructions)

typedef float f32x4 __attribute__((ext_vector_type(4)));

// LDS dest must be wave-uniform AND compile-time-selected (round-6 lesson:
// runtime-indexed buffer select defeats uniformity analysis -> 20x cliff).
#define GLOAD_LDS16(gsrc, ldst)                                                \
    __builtin_amdgcn_global_load_lds(                                          \
        (const __attribute__((address_space(1))) unsigned int*)(gsrc),         \
        (__attribute__((address_space(3))) unsigned int*)(ldst), 16, 0, 0)

// Stage x chunk `ch` into static buffer XB: 8 instr/wave, each = 8 tokens x
// one full 128B line = 1KB linear LDS dest (R5's proven pattern).
#define STAGE_X(ch, XB) do {                                                   \
    const int dd_ = (ch) * CH;                                                 \
    _Pragma("unroll")                                                          \
    for (int kk = 0; kk < 8; ++kk) {                                           \
        const int k_ = wid * 8 + kk;                                           \
        const float* src_ =                                                    \
            x + (size_t)(tok0 + k_ * 8 + lrow) * DD + dd_ + lcol;              \
        GLOAD_LDS16(src_, &XB[k_ * GRP]);                                      \
    }                                                                          \
} while (0)

// Stage w chunk (24 rows x 32 floats, clamp-dup pad rows): wave 0, 3 instrs.
#define STAGE_W(ch, WB) do {                                                   \
    const int dd_ = (ch) * CH;                                                 \
    if (wid == 0) {                                                            \
        _Pragma("unroll")                                                      \
        for (int m = 0; m < 3; ++m) {                                          \
            GLOAD_LDS16(wrow[m] + dd_ + lcol, &WB[m * 256]);                   \
        }                                                                      \
    }                                                                          \
} while (0)

#define COMPUTE(XB, WB) do {                                                   \
    _Pragma("unroll")                                                          \
    for (int g = 0; g < 8; ++g) {                                              \
        const f32x4 xv = *(const f32x4*)&XB[xoff + g * 4];                     \
        _Pragma("unroll")                                                      \
        for (int o = 0; o < NOUT; ++o) {                                       \
            const f32x4 w = *(const f32x4*)&WB[o * CH + g * 4];                \
            float a = acc[o];                                                  \
            a = fmaf(xv.x, w.x, a);                                            \
            a = fmaf(xv.y, w.y, a);                                            \
            a = fmaf(xv.z, w.z, a);                                            \
            a = fmaf(xv.w, w.w, a);                                            \
            acc[o] = a;                                                        \
        }                                                                      \
    }                                                                          \
} while (0)

// Double-buffered prefetch with STATIC buffers, R5 geometry (TPB=256, CH=32):
// stage(B) -> compute(A) -> barrier -> stage(A) -> compute(B) -> barrier.
// Each chunk's HBM transfer overlaps the other buffer's compute; 2 blocks/CU
// (8 waves) stagger to fill the drain bubbles.
__global__ __launch_bounds__(TPB, 2) void router_k(
    const float* __restrict__ x,        // [NB, DD]
    const float* __restrict__ group_w,  // [NG, DD]
    const float* __restrict__ group_b,  // [NG]
    const float* __restrict__ in_w,     // [NG*NGS, DD]
    const float* __restrict__ in_b,     // [NG, NGS]
    const int*   __restrict__ experts,  // [NG, NGS]
    float*       __restrict__ out)      // [2*NB*2]: indices then weights, fp32
{
    __shared__ float xbA[NXG * GRP];    // 33280 B
    __shared__ float xbB[NXG * GRP];    // 33280 B
    __shared__ float wbA[WROWS * CH];   //  3072 B
    __shared__ float wbB[WROWS * CH];   //  3072 B

    const int tid  = threadIdx.x;
    const int wid  = tid >> 6;          // 0..3
    const int lane = tid & 63;
    const int tok0 = blockIdx.x * TOKS;

    const int lrow = lane >> 3;         // token-in-group for staging
    const int lcol = (lane & 7) * 4;    // float offset within 128B line

    // Weight source rows for the 3 staging instructions (clamp-dup pads).
    const float* wrow[3];
#pragma unroll
    for (int m = 0; m < 3; ++m) {
        int R = m * 8 + lrow;
        if (R > 19) R = 19;
        wrow[m] = (R < NG) ? (group_w + (size_t)R * DD)
                           : (in_w + (size_t)(R - NG) * DD);
    }

    // This thread's token slot inside a buffer (token tid of the block).
    const int xoff = (tid >> 3) * GRP + (tid & 7) * CH;

    float acc[NOUT];
#pragma unroll
    for (int o = 0; o < NOUT; ++o) acc[o] = 0.f;

    STAGE_X(0, xbA);
    STAGE_W(0, wbA);
    __syncthreads();   // buf A ready

#pragma unroll 1
    for (int ch = 0; ch < NCHUNK; ch += 2) {
        STAGE_X(ch + 1, xbB);            // transfer overlaps compute(A)
        STAGE_W(ch + 1, wbB);
        COMPUTE(xbA, wbA);
        __syncthreads();                 // B landed; all readers done with A

        if (ch + 2 < NCHUNK) { STAGE_X(ch + 2, xbA); STAGE_W(ch + 2, wbA); }
        COMPUTE(xbB, wbB);
        if (ch + 2 < NCHUNK) __syncthreads();  // A landed; done reading B
    }

    // ---- epilogue (one token per thread) ----
    const int t = tok0 + tid;

    // group argmax (first-max tie-break, matches jnp.argmax)
    float gl[NG];
#pragma unroll
    for (int g = 0; g < NG; ++g) gl[g] = acc[g] + group_b[g];
    int bg = 0;
    float bv = gl[0];
#pragma unroll
    for (int g = 1; g < NG; ++g)
        if (gl[g] > bv) { bv = gl[g]; bg = g; }

    // select chosen group's in-logits without runtime indexing
    float il[NGS];
#pragma unroll
    for (int k = 0; k < NGS; ++k) il[k] = 0.f;
#pragma unroll
    for (int g = 0; g < NG; ++g) {
        const bool sel = (g == bg);
#pragma unroll
        for (int k = 0; k < NGS; ++k)
            il[k] = sel ? acc[NG + g * NGS + k] : il[k];
    }
#pragma unroll
    for (int k = 0; k < NGS; ++k) il[k] += in_b[bg * NGS + k];

    // softmax (fp32, subtract-max)
    float m = fmaxf(fmaxf(il[0], il[1]), fmaxf(il[2], il[3]));
    float p[NGS];
    float s = 0.f;
#pragma unroll
    for (int k = 0; k < NGS; ++k) { p[k] = expf(il[k] - m); s += p[k]; }
    const float inv = 1.0f / s;
#pragma unroll
    for (int k = 0; k < NGS; ++k) p[k] *= inv;

    // top-2 (descending, lower-index-on-tie, matches lax.top_k)
    int i1 = 0;
    float v1 = p[0];
#pragma unroll
    for (int k = 1; k < NGS; ++k)
        if (p[k] > v1) { v1 = p[k]; i1 = k; }
    int i2 = -1;
    float v2 = -3.0e38f;
#pragma unroll
    for (int k = 0; k < NGS; ++k)
        if (k != i1 && p[k] > v2) { v2 = p[k]; i2 = k; }

    const int id1 = experts[bg * NGS + i1];
    const int id2 = experts[bg * NGS + i2];

    float2* outi = reinterpret_cast<float2*>(out);
    float2* outw = reinterpret_cast<float2*>(out + (size_t)NB * 2);
    outi[t] = make_float2((float)id1, (float)id2);
    outw[t] = make_float2(v1, v2);
}

extern "C" void kernel_launch(void* const* d_in, const int* in_sizes, int n_in,
                              void* d_out, int out_size, void* d_ws, size_t ws_size,
                              hipStream_t stream) {
    const float* x  = (const float*)d_in[0];
    const float* gw = (const float*)d_in[1];
    const float* gb = (const float*)d_in[2];
    const float* iw = (const float*)d_in[3];
    const float* ib = (const float*)d_in[4];
    const int*   et = (const int*)d_in[5];
    float* out = (float*)d_out;

    router_k<<<dim3(NB / TOKS), dim3(TPB), 0, stream>>>(x, gw, gb, iw, ib, et, out);
}

// Round 9
// 1701.500 us; speedup vs baseline: 1.2514x; 1.2514x over previous
//
#include <hip/hip_runtime.h>
#include <math.h>

#define NB     262144   // batch (tokens)
#define DD     512      // d_routing
#define NG     4        // groups
#define NGS    4        // group size
#define NOUT   20       // 4 group logits + 16 in-group logits

#define TPB    512      // 8 waves per block, 1 block/CU (LDS-capped)
#define TOKS   512      // tokens per block
#define CH     32       // floats of D per chunk per token (one full 128B line)
#define NCHUNK 16       // DD / CH
#define GRP    260      // 8 tokens * 32 floats + 4 pad floats

// Dynamic-LDS float offsets (all compile-time constants off one base).
#define XA_OFF 0
#define XB_OFF (64 * GRP)              // 16640
#define WA_OFF (2 * 64 * GRP)          // 33280 (24 rows x 32 floats)
#define WB_OFF (2 * 64 * GRP + 768)    // 34048
#define LDS_FLOATS (2 * 64 * GRP + 2 * 768)   // 34816 floats = 139264 B

typedef float f32x4 __attribute__((ext_vector_type(4)));

#define GLOAD_LDS16(gsrc, ldst)                                                \
    __builtin_amdgcn_global_load_lds(                                          \
        (const __attribute__((address_space(1))) unsigned int*)(gsrc),         \
        (__attribute__((address_space(3))) unsigned int*)(ldst), 16, 0, 0)

// Stage chunk `ch`: wave0 issues w FIRST (3 instr), then every wave 8 x-instrs.
// All LDS dests are compile-time offsets (static buffer symbols; R6/R8 lesson).
#define STAGE(ch, XOFF, WOFF) do {                                             \
    const int dd_ = (ch) * CH;                                                 \
    if (wid == 0) {                                                            \
        GLOAD_LDS16(wsrc0 + dd_, &lds[(WOFF) + 0 * 256]);                      \
        GLOAD_LDS16(wsrc1 + dd_, &lds[(WOFF) + 1 * 256]);                      \
        GLOAD_LDS16(wsrc2 + dd_, &lds[(WOFF) + 2 * 256]);                      \
    }                                                                          \
    _Pragma("unroll")                                                          \
    for (int m = 0; m < 8; ++m) {                                              \
        GLOAD_LDS16(xsrc + (size_t)m * (8 * DD) + dd_,                         \
                    &lds[(XOFF) + (8 * wid + m) * GRP]);                       \
    }                                                                          \
} while (0)

// o-split-4 compute: lane (q=lane>>4, slot=lane&15) does outputs q*5..q*5+4
// for tokens 64*wid + slot + 16*j, j=0..3. x-reads: 16 distinct addrs,
// 4-lane broadcast, 2 addrs/bank-quad (free). w-reads: 4 distinct rows,
// distinct quads (free). 72 LDS instrs/wave/chunk vs 176 unsplit.
#define COMPUTE(XOFF, WOFF) do {                                               \
    _Pragma("unroll")                                                          \
    for (int g = 0; g < 8; ++g) {                                              \
        const f32x4 xv0 = *(const f32x4*)&lds[(XOFF) + xo0 + g * 4];           \
        const f32x4 xv1 = *(const f32x4*)&lds[(XOFF) + xo1 + g * 4];           \
        const f32x4 xv2 = *(const f32x4*)&lds[(XOFF) + xo2 + g * 4];           \
        const f32x4 xv3 = *(const f32x4*)&lds[(XOFF) + xo3 + g * 4];           \
        _Pragma("unroll")                                                      \
        for (int oo = 0; oo < 5; ++oo) {                                       \
            const f32x4 wv =                                                   \
                *(const f32x4*)&lds[(WOFF) + (q5 + oo) * CH + g * 4];          \
            acc0[oo] = fmaf(xv0.x, wv.x, acc0[oo]);                            \
            acc0[oo] = fmaf(xv0.y, wv.y, acc0[oo]);                            \
            acc0[oo] = fmaf(xv0.z, wv.z, acc0[oo]);                            \
            acc0[oo] = fmaf(xv0.w, wv.w, acc0[oo]);                            \
            acc1[oo] = fmaf(xv1.x, wv.x, acc1[oo]);                            \
            acc1[oo] = fmaf(xv1.y, wv.y, acc1[oo]);                            \
            acc1[oo] = fmaf(xv1.z, wv.z, acc1[oo]);                            \
            acc1[oo] = fmaf(xv1.w, wv.w, acc1[oo]);                            \
            acc2[oo] = fmaf(xv2.x, wv.x, acc2[oo]);                            \
            acc2[oo] = fmaf(xv2.y, wv.y, acc2[oo]);                            \
            acc2[oo] = fmaf(xv2.z, wv.z, acc2[oo]);                            \
            acc2[oo] = fmaf(xv2.w, wv.w, acc2[oo]);                            \
            acc3[oo] = fmaf(xv3.x, wv.x, acc3[oo]);                            \
            acc3[oo] = fmaf(xv3.y, wv.y, acc3[oo]);                            \
            acc3[oo] = fmaf(xv3.z, wv.z, acc3[oo]);                            \
            acc3[oo] = fmaf(xv3.w, wv.w, acc3[oo]);                            \
        }                                                                      \
    }                                                                          \
} while (0)

#define SBAR0() __builtin_amdgcn_sched_barrier(0)
#define BARRIER() do { __builtin_amdgcn_s_barrier(); SBAR0(); } while (0)
#define WAIT_VM8() do {                                                        \
    asm volatile("s_waitcnt vmcnt(8)" ::: "memory"); SBAR0(); } while (0)
#define WAIT_VM0() do {                                                        \
    asm volatile("s_waitcnt vmcnt(0)" ::: "memory"); SBAR0(); } while (0)

__global__ __launch_bounds__(TPB, 2) void router_k(
    const float* __restrict__ x,        // [NB, DD]
    const float* __restrict__ group_w,  // [NG, DD]
    const float* __restrict__ group_b,  // [NG]
    const float* __restrict__ in_w,     // [NG*NGS, DD]
    const float* __restrict__ in_b,     // [NG, NGS]
    const int*   __restrict__ experts,  // [NG, NGS]
    float*       __restrict__ out)      // [2*NB*2]: indices then weights, fp32
{
    extern __shared__ float lds[];

    const int tid  = threadIdx.x;
    const int wid  = tid >> 6;          // 0..7
    const int lane = tid & 63;
    const int slot = lane & 15;
    const int q5   = (lane >> 4) * 5;   // this lane's output base
    const int tok0 = blockIdx.x * TOKS;

    // ---- staging source pointers (per-lane; LDS dests are linear) ----
    const float* xsrc =
        x + (size_t)(tok0 + 64 * wid + (lane >> 3)) * DD + (lane & 7) * 4;
    int r0 = (lane >> 3);               // rows 0..7
    int r1 = 8 + (lane >> 3);           // rows 8..15
    int r2 = 16 + (lane >> 3);          // rows 16..23 -> clamp
    if (r2 > 19) r2 = 19;
    const float* wsrc0 = ((r0 < NG) ? (group_w + (size_t)r0 * DD)
                                    : (in_w + (size_t)(r0 - NG) * DD)) + (lane & 7) * 4;
    const float* wsrc1 = (in_w + (size_t)(r1 - NG) * DD) + (lane & 7) * 4;
    const float* wsrc2 = (in_w + (size_t)(r2 - NG) * DD) + (lane & 7) * 4;

    // ---- compute-side x offsets (floats), token j at 64*wid+slot+16*j ----
    const int xo0 = ((64 * wid + slot +  0) >> 3) * GRP + (slot & 7) * CH;
    const int xo1 = ((64 * wid + slot + 16) >> 3) * GRP + (slot & 7) * CH;
    const int xo2 = ((64 * wid + slot + 32) >> 3) * GRP + (slot & 7) * CH;
    const int xo3 = ((64 * wid + slot + 48) >> 3) * GRP + (slot & 7) * CH;

    float acc0[5], acc1[5], acc2[5], acc3[5];
#pragma unroll
    for (int oo = 0; oo < 5; ++oo) {
        acc0[oo] = 0.f; acc1[oo] = 0.f; acc2[oo] = 0.f; acc3[oo] = 0.f;
    }

    // ---- prologue: stage chunks 0 (A) and 1 (B) ----
    STAGE(0, XA_OFF, WA_OFF);
    STAGE(1, XB_OFF, WB_OFF);
    WAIT_VM8();    // set0 landed (wave0: +set1's w); set1's 8 x stay in flight
    BARRIER();     // set0 visible to all waves

    // ---- main pipeline: counted vmcnt, loads always in flight ----
#pragma unroll 1
    for (int it = 0; it < 7; ++it) {
        const int ch = 2 * it;
        COMPUTE(XA_OFF, WA_OFF);            // chunk ch
        BARRIER();                          // all readers done with A
        STAGE(ch + 2, XA_OFF, WA_OFF);
        WAIT_VM8();                         // chunk ch+1 landed
        BARRIER();                          // ...and visible (incl. wave0's w)
        COMPUTE(XB_OFF, WB_OFF);            // chunk ch+1
        BARRIER();                          // all readers done with B
        STAGE(ch + 3, XB_OFF, WB_OFF);
        WAIT_VM8();                         // chunk ch+2 landed
        BARRIER();
    }
    COMPUTE(XA_OFF, WA_OFF);                // chunk 14
    WAIT_VM0();                             // chunk 15 landed
    BARRIER();
    COMPUTE(XB_OFF, WB_OFF);                // chunk 15

    // ---- epilogue: reassemble o-split via LDS scratch (xbA is dead) ----
    __syncthreads();                        // everyone done with compute reads
    float* ep = &lds[XA_OFF];               // 512 tokens x 20 floats = 40KB
#pragma unroll
    for (int oo = 0; oo < 5; ++oo) {
        ep[(64 * wid + slot +  0) * NOUT + q5 + oo] = acc0[oo];
        ep[(64 * wid + slot + 16) * NOUT + q5 + oo] = acc1[oo];
        ep[(64 * wid + slot + 32) * NOUT + q5 + oo] = acc2[oo];
        ep[(64 * wid + slot + 48) * NOUT + q5 + oo] = acc3[oo];
    }
    __syncthreads();

    // One token per thread: tid owns token tok0+tid.
    float l[NOUT];
#pragma unroll
    for (int o = 0; o < NOUT; ++o) l[o] = ep[tid * NOUT + o];

    const int t = tok0 + tid;

    // group argmax (first-max tie-break, matches jnp.argmax)
    float gl[NG];
#pragma unroll
    for (int g = 0; g < NG; ++g) gl[g] = l[g] + group_b[g];
    int bg = 0;
    float bv = gl[0];
#pragma unroll
    for (int g = 1; g < NG; ++g)
        if (gl[g] > bv) { bv = gl[g]; bg = g; }

    // select chosen group's in-logits without runtime indexing
    float il[NGS];
#pragma unroll
    for (int k = 0; k < NGS; ++k) il[k] = 0.f;
#pragma unroll
    for (int g = 0; g < NG; ++g) {
        const bool sel = (g == bg);
#pragma unroll
        for (int k = 0; k < NGS; ++k)
            il[k] = sel ? l[NG + g * NGS + k] : il[k];
    }
#pragma unroll
    for (int k = 0; k < NGS; ++k) il[k] += in_b[bg * NGS + k];

    // softmax (fp32, subtract-max)
    float m = fmaxf(fmaxf(il[0], il[1]), fmaxf(il[2], il[3]));
    float p[NGS];
    float s = 0.f;
#pragma unroll
    for (int k = 0; k < NGS; ++k) { p[k] = expf(il[k] - m); s += p[k]; }
    const float inv = 1.0f / s;
#pragma unroll
    for (int k = 0; k < NGS; ++k) p[k] *= inv;

    // top-2 (descending, lower-index-on-tie, matches lax.top_k)
    int i1 = 0;
    float v1 = p[0];
#pragma unroll
    for (int k = 1; k < NGS; ++k)
        if (p[k] > v1) { v1 = p[k]; i1 = k; }
    int i2 = -1;
    float v2 = -3.0e38f;
#pragma unroll
    for (int k = 0; k < NGS; ++k)
        if (k != i1 && p[k] > v2) { v2 = p[k]; i2 = k; }

    const int id1 = experts[bg * NGS + i1];
    const int id2 = experts[bg * NGS + i2];

    float2* outi = reinterpret_cast<float2*>(out);
    float2* outw = reinterpret_cast<float2*>(out + (size_t)NB * 2);
    outi[t] = make_float2((float)id1, (float)id2);
    outw[t] = make_float2(v1, v2);
}

extern "C" void kernel_launch(void* const* d_in, const int* in_sizes, int n_in,
                              void* d_out, int out_size, void* d_ws, size_t ws_size,
                              hipStream_t stream) {
    const float* x  = (const float*)d_in[0];
    const float* gw = (const float*)d_in[1];
    const float* gb = (const float*)d_in[2];
    const float* iw = (const float*)d_in[3];
    const float* ib = (const float*)d_in[4];
    const int*   et = (const int*)d_in[5];
    float* out = (float*)d_out;

    router_k<<<dim3(NB / TOKS), dim3(TPB), LDS_FLOATS * 4, stream>>>(
        x, gw, gb, iw, ib, et, out);
}